// Round 9
// baseline (195.539 us; speedup 1.0000x reference)
//
#include <hip/hip_runtime.h>

#define LQ 1024
#define EMB 2048
#define NH 16
#define HD 128
#define RSCALE 0.022097086912079608f   /* 1/sqrt(2048) */

typedef unsigned short u16x8 __attribute__((ext_vector_type(8)));
typedef __bf16 bf16x8 __attribute__((ext_vector_type(8)));
typedef float f32x4 __attribute__((ext_vector_type(4)));
typedef short s16x4 __attribute__((ext_vector_type(4)));

typedef const __attribute__((address_space(1))) unsigned int* gas_t;
typedef __attribute__((address_space(3))) unsigned int* las_t;

__device__ __forceinline__ void glds16(const void* g, void* l){
  __builtin_amdgcn_global_load_lds((gas_t)g, (las_t)l, 16, 0, 0);
}
__device__ __forceinline__ unsigned short f2b(float f){
  unsigned int x = __float_as_uint(f);
  return (unsigned short)((x + 0x7fffu + ((x >> 16) & 1u)) >> 16);
}
// native RNE f32->bf16 (v_cvt on gfx950) — identical bits to f2b, 1 op not 4
__device__ __forceinline__ unsigned short f2bu(float f){
  union { __bf16 h; unsigned short u; } c; c.h = (__bf16)f; return c.u;
}
__device__ __forceinline__ short f2bs(float f){
  union { __bf16 h; short s; } c; c.h = (__bf16)f; return c.s;
}
__device__ __forceinline__ bf16x8 as_bf(u16x8 u){
  union { u16x8 u; bf16x8 b; } c; c.u = u; return c.b;
}
// K=16 bf16 MFMA (v_mfma_f32_16x16x16_bf16, gfx90a-lineage builtin, valid gfx950)
__device__ __forceinline__ f32x4 mfma16(s16x4 a, s16x4 b, f32x4 c){
  return __builtin_amdgcn_mfma_f32_16x16x16bf16_1k(a, b, c, 0, 0, 0);
}

// ---- K1 (fused): RoPE + projections + V-fragment emit + prep slice --------
// grid (512, 4):
//   y=0: V projection -> fragment-ordered vtF (one (head,k-tile) per block)
//   y=1: K projection (rope) -> kp (n,h,l,d)
//   y=2: Q projection (rope, *RSCALE) -> qp (n,h,l,d)
//   y=3: prep: Wo fp32->bf16 + mask bit-pack
// r9: ALL X/XM loads issued at the very top (before sincos and the W phase)
// so ~512B/lane is in flight across both staging epochs — k_proj measured
// 1.9 TB/s with every pipe idle = classic MLP starvation (Little's law).
__global__ __launch_bounds__(256) void k_proj(
    const float* __restrict__ vals, const float* __restrict__ keys,
    const float* __restrict__ qrys,
    const float* __restrict__ Wv, const float* __restrict__ Wk,
    const float* __restrict__ Wq,
    const float* __restrict__ Wo, const int* __restrict__ M,
    unsigned short* __restrict__ kp, unsigned short* __restrict__ qp,
    unsigned short* __restrict__ vtF, unsigned short* __restrict__ Wob,
    unsigned long long* __restrict__ Mb)
{
  __shared__ unsigned short Xs[64 * 136];
  __shared__ unsigned short Ws[128 * 136];
  __shared__ float scC[4 * 128], scS[4 * 128];
  int t = threadIdx.x;
  int which = blockIdx.y;

  if (which == 3) {                       // ---- prep slice ----
    int bx = blockIdx.x;
    #pragma unroll
    for (int k = 0; k < 8; ++k) {
      int i = (bx * 2048 + k * 256 + t) * 4;
      float4 f = *(const float4*)&Wo[i];
      ushort4 u;
      u.x = f2bu(f.x); u.y = f2bu(f.y); u.z = f2bu(f.z); u.w = f2bu(f.w);
      *(ushort4*)&Wob[i] = u;
    }
    int w = t >> 6, lane = t & 63;
    #pragma unroll
    for (int i = 0; i < 16; ++i) {
      int w_idx = bx * 64 + w * 16 + i;   // < 32768
      int n = w_idx >> 14, row = (w_idx >> 4) & 1023, wc = w_idx & 15;
      int v = M[(size_t)n * (LQ * LQ) + (size_t)row * LQ + wc * 64 + lane];
      unsigned long long b = __ballot(v != 0);
      if (lane == 0) Mb[w_idx] = b;
    }
    return;
  }

  const float* X; const float* W; bool rope;
  if (which == 0)      { X = vals; W = Wv; rope = false; }
  else if (which == 1) { X = keys; W = Wk; rope = true;  }
  else                 { X = qrys; W = Wq; rope = true;  }
  float qs = (which == 2) ? RSCALE : 1.0f;

  int w = t >> 6, lane = t & 63, quad = lane >> 4, n16 = lane & 15;

  // ---- issue ALL X (+mirror) loads first: max bytes in flight ----
  float4 xr[8], xmr[8];
  int bh0 = blockIdx.x >> 4, kt0 = blockIdx.x & 15;  // V decode
  int m0 = blockIdx.x * 64;
  if (which == 0) {
    int n = bh0 >> 4, h = bh0 & 15;
    #pragma unroll
    for (int i = 0; i < 8; ++i) {
      int fi = t + 256 * i;
      int row = fi >> 5, dq = (fi & 31) * 4;
      size_t gr = (size_t)n * 16384 + (size_t)(kt0 * 64 + row) * 16 + h;
      xr[i] = *(const float4*)&X[gr * HD + dq];
    }
  } else {
    #pragma unroll
    for (int i = 0; i < 8; ++i) {
      int fi = t + 256 * i;
      int row = fi >> 5, dq = (fi & 31) * 4;
      int gr = m0 + row;
      xr[i]  = *(const float4*)&X[(size_t)gr * HD + dq];
      xmr[i] = *(const float4*)&X[(size_t)gr * HD + (124 - dq)];
    }
  }

  // sincos (pure VALU — overlaps the in-flight loads)
  if (rope) {
    int l0 = (blockIdx.x * 4) & 1023;
    #pragma unroll
    for (int i = 0; i < 2; ++i) {
      int idx = t + 256 * i;
      int li = idx >> 7, d = idx & 127, j = d & 63;
      float inv = 1.0f / powf(10000.0f, (float)(2 * j) * 0.0078125f);
      float ang = (float)(l0 + li) * inv;
      scC[idx] = cosf(ang);
      scS[idx] = sinf(ang);
    }
  }

  // stage W (fp32 -> bf16) into LDS (second load epoch, overlapped with X)
  #pragma unroll
  for (int i = 0; i < 8; ++i) {
    int ci = t + 256 * i;
    int row = ci >> 4, ch = ci & 15;
    float4 a = *(const float4*)&W[row * 128 + ch * 8];
    float4 b = *(const float4*)&W[row * 128 + ch * 8 + 4];
    u16x8 u;
    u[0]=f2bu(a.x); u[1]=f2bu(a.y); u[2]=f2bu(a.z); u[3]=f2bu(a.w);
    u[4]=f2bu(b.x); u[5]=f2bu(b.y); u[6]=f2bu(b.z); u[7]=f2bu(b.w);
    *(u16x8*)&Ws[row * 136 + ch * 8] = u;
  }
  __syncthreads();                        // Ws + sc ready

  // X convert + store (loads landed long ago)
  if (which == 0) {
    #pragma unroll
    for (int i = 0; i < 8; ++i) {
      int fi = t + 256 * i;
      int row = fi >> 5, dq = (fi & 31) * 4;
      ushort4 u;
      u.x = f2bu(xr[i].x); u.y = f2bu(xr[i].y);
      u.z = f2bu(xr[i].z); u.w = f2bu(xr[i].w);
      *(ushort4*)&Xs[row * 136 + dq] = u;
    }
  } else {
    #pragma unroll
    for (int i = 0; i < 8; ++i) {
      int fi = t + 256 * i;
      int row = fi >> 5, dq = (fi & 31) * 4;
      int li = row >> 4;
      float4 c  = *(const float4*)&scC[li * 128 + dq];
      float4 s  = *(const float4*)&scS[li * 128 + dq];
      ushort4 u;
      u.x = f2bu(xr[i].x * c.x + xmr[i].w * s.x);
      u.y = f2bu(xr[i].y * c.y + xmr[i].z * s.y);
      u.z = f2bu(xr[i].z * c.z + xmr[i].y * s.z);
      u.w = f2bu(xr[i].w * c.w + xmr[i].x * s.w);
      *(ushort4*)&Xs[row * 136 + dq] = u;
    }
  }
  __syncthreads();

  f32x4 of[4][2];
  #pragma unroll
  for (int a = 0; a < 4; ++a)
    { of[a][0] = (f32x4){0.f,0.f,0.f,0.f}; of[a][1] = (f32x4){0.f,0.f,0.f,0.f}; }

  #pragma unroll
  for (int kd = 0; kd < 4; ++kd) {
    bf16x8 bfr[2];
    #pragma unroll
    for (int b2 = 0; b2 < 2; ++b2)
      bfr[b2] = as_bf(*(const u16x8*)&Ws[(w * 32 + b2 * 16 + n16) * 136 + kd * 32 + quad * 8]);
    #pragma unroll
    for (int a = 0; a < 4; ++a) {
      bf16x8 af = as_bf(*(const u16x8*)&Xs[(a * 16 + n16) * 136 + kd * 32 + quad * 8]);
      of[a][0] = __builtin_amdgcn_mfma_f32_16x16x32_bf16(af, bfr[0], of[a][0], 0, 0, 0);
      of[a][1] = __builtin_amdgcn_mfma_f32_16x16x32_bf16(af, bfr[1], of[a][1], 0, 0, 0);
    }
  }

  if (which == 0) {
    // V: fragment-ordered vtF, PAIRED layout (16B/lane coalesced).
    // of[a][b2][r] = V[kpos = a*16+quad*4+r][d = (w*2+b2)*16 + n16]
    size_t vbase = (size_t)bh0 * (LQ * HD) + (size_t)kt0 * 8192;
    #pragma unroll
    for (int a = 0; a < 4; ++a) {
      u16x8 u;
      u[0]=f2bu(of[a][0][0]); u[1]=f2bu(of[a][0][1]);
      u[2]=f2bu(of[a][0][2]); u[3]=f2bu(of[a][0][3]);
      u[4]=f2bu(of[a][1][0]); u[5]=f2bu(of[a][1][1]);
      u[6]=f2bu(of[a][1][2]); u[7]=f2bu(of[a][1][3]);
      *(u16x8*)&vtF[vbase + (size_t)(((a * 4 + w) * 64 + (quad * 16 + n16)) * 8)] = u;
    }
  } else {
    // K/Q: route fragments through LDS (Ws dead after MFMA) -> 16B coalesced
    unsigned short* OUT = (which == 1) ? kp : qp;
    __syncthreads();                       // everyone done reading Ws
    #pragma unroll
    for (int a = 0; a < 4; ++a)
      #pragma unroll
      for (int b2 = 0; b2 < 2; ++b2)
        #pragma unroll
        for (int r = 0; r < 4; ++r)
          Ws[(a * 16 + quad * 4 + r) * 136 + w * 32 + b2 * 16 + n16] =
              f2bu(of[a][b2][r] * qs);
    __syncthreads();
    #pragma unroll
    for (int i = 0; i < 4; ++i) {
      int chunk = t + 256 * i;             // 1024 chunks of 8 shorts
      int row = chunk >> 4, dc = chunk & 15;
      u16x8 v = *(const u16x8*)&Ws[row * 136 + dc * 8];
      int m = m0 + row;
      int n = m >> 14, l = (m >> 4) & 1023, h = m & 15;
      *(u16x8*)&OUT[(((size_t)(n * NH + h)) * LQ + l) * HD + dc * 8] = v;
    }
  }
}

// ---------------- K2: MFMA flash attention, S^T trick, no P round-trip ------
// r9: epilogue routes the normalized output through a 16KB LDS overlay so
// ALL 8 waves emit coalesced 16B ao-stores (was: grp0-only 2B scattered).
__global__ __launch_bounds__(512) void k_attn(
    const unsigned short* __restrict__ qp, const unsigned short* __restrict__ kp,
    const unsigned short* __restrict__ vtF, const unsigned long long* __restrict__ Mb,
    unsigned short* __restrict__ ao)
{
  __shared__ unsigned short KsF[2][8192];   // [tile][kd][c][lane] 16B chunks
  __shared__ unsigned short VsF[2][8192];   // [tile][c][c2p][lane] 16B paired slots
  __shared__ float ls[8][16];
  int t = threadIdx.x, w = t >> 6, lane = t & 63, quad = lane >> 4, n16 = lane & 15;
  int grp = w >> 2, wq = w & 3;                // k-group, q-row wave within group
  // XCD swizzle: cluster one head's q-tiles on one XCD so its K/V stays in L2.
  int lin = blockIdx.y * gridDim.x + blockIdx.x;
  int xcd = lin & 7, j = lin >> 3;
  int bh = xcd + 8 * (j >> 4);
  int q0 = (j & 15) * 64;
  int nIdx = bh >> 4, h = bh & 15;
  size_t base = (size_t)bh * LQ * HD;
  const unsigned short* Q = qp + base;
  const unsigned short* K = kp + base;
  const unsigned short* VF = vtF + base;       // fragment-ordered tiles

  // Q fragments (B-operand of S^T MFMA): B[n=q=n16][k=d=kd*32+quad*8+j]
  bf16x8 qf[4];
  #pragma unroll
  for (int kd = 0; kd < 4; ++kd)
    qf[kd] = as_bf(*(const u16x8*)&Q[(size_t)(q0 + wq * 16 + n16) * HD + kd * 32 + quad * 8]);

  // one mask word per lane per tile: q = n16
  const unsigned long long* MbRow =
      Mb + ((size_t)nIdx * LQ + q0 + wq * 16 + n16) * 16;

  f32x4 of[8];
  #pragma unroll
  for (int c = 0; c < 8; ++c) of[c] = (f32x4){0.f, 0.f, 0.f, 0.f};
  float lp = 0.f;                          // per-lane partial of l[q=n16]

  for (int p = 0; p < 8; ++p) {
    int k0 = p * 128;
    __syncthreads();                       // all waves done reading both buffers
    // stage tile pair (2p -> buf0, 2p+1 -> buf1), all 8 waves cooperate
    #pragma unroll
    for (int jj = 0; jj < 2; ++jj) {
      int kt = 2 * p + jj;
      #pragma unroll
      for (int i = 0; i < 2; ++i) {
        int D = t + 512 * i;               // 16B chunk id 0..1023
        int nn = D & 15, qq = (D >> 4) & 3, cc = (D >> 6) & 3, kd = D >> 8;
        glds16(&K[(size_t)(k0 + jj * 64 + cc * 16 + nn) * HD + (kd * 4 + qq) * 8],
               &KsF[jj][(size_t)D * 8]);
        glds16(&VF[(size_t)kt * 8192 + (size_t)D * 8],
               &VsF[jj][(size_t)D * 8]);
      }
    }
    unsigned long long mq = MbRow[2 * p + grp];
    __syncthreads();                       // implicit vmcnt(0): staged data ready

    // single variable 64-bit shift; per-bit extracts below are const-shift
    unsigned long long msh = mq >> (quad * 4);

    // ---- S^T = K Q^T : rows kpos, cols q (group's own tile) ----
    f32x4 sf[4];
    #pragma unroll
    for (int c = 0; c < 4; ++c) sf[c] = (f32x4){0.f, 0.f, 0.f, 0.f};
    __builtin_amdgcn_s_setprio(1);
    #pragma unroll
    for (int kd = 0; kd < 4; ++kd) {
      #pragma unroll
      for (int c = 0; c < 4; ++c) {
        bf16x8 kv = as_bf(*(const u16x8*)&KsF[grp][((kd * 4 + c) * 64 + lane) * 8]);
        sf[c] = __builtin_amdgcn_mfma_f32_16x16x32_bf16(kv, qf[kd], sf[c], 0, 0, 0);
      }
    }
    __builtin_amdgcn_s_setprio(0);
    // ---- softmax numerators + PV (P stays in registers) ----
    #pragma unroll
    for (int c = 0; c < 4; ++c) {
      s16x4 pa;
      #pragma unroll
      for (int r = 0; r < 4; ++r) {
        int bit = (int)((msh >> (c * 16 + r)) & 1ull);
        float p = bit ? __expf(sf[c][r]) : 0.f;
        lp += p;
        pa[r] = f2bs(p);
      }
      __builtin_amdgcn_s_setprio(1);
      #pragma unroll
      for (int c2p = 0; c2p < 4; ++c2p) {
        u16x8 vv2 = *(const u16x8*)&VsF[grp][((c * 4 + c2p) * 64 + lane) * 8];
        s16x4 vlo = { (short)vv2[0], (short)vv2[1], (short)vv2[2], (short)vv2[3] };
        s16x4 vhi = { (short)vv2[4], (short)vv2[5], (short)vv2[6], (short)vv2[7] };
        of[2 * c2p]     = mfma16(pa, vlo, of[2 * c2p]);
        of[2 * c2p + 1] = mfma16(pa, vhi, of[2 * c2p + 1]);
      }
      __builtin_amdgcn_s_setprio(0);
    }
  }

  // ---- combine: l via ls; of via 32KB OF overlay (KsF); normalized bf16
  // result via 16KB AO overlay (VsF) -> coalesced 16B stores by all waves.
  __syncthreads();                         // all compute done before overlays
  {
    float s = lp;
    s += __shfl_xor(s, 16);
    s += __shfl_xor(s, 32);
    ls[w][n16] = s;
  }
  float* OF = (float*)&KsF[0][0];          // 64 q x 128 d f32 = 32 KB
  unsigned short* AO = &VsF[0][0];         // 64 q x 128 d bf16 = 16 KB
  if (grp == 1) {
    #pragma unroll
    for (int c2 = 0; c2 < 8; ++c2) {
      #pragma unroll
      for (int r = 0; r < 4; ++r) {
        OF[(wq * 16 + quad * 4 + r) * 128 + c2 * 16 + n16] = of[c2][r];
      }
    }
  }
  __syncthreads();
  if (grp == 0) {
    float linv[4];
    #pragma unroll
    for (int r = 0; r < 4; ++r)
      linv[r] = 1.0f / fmaxf(ls[wq][quad * 4 + r] + ls[wq + 4][quad * 4 + r], 1e-30f);
    #pragma unroll
    for (int c2 = 0; c2 < 8; ++c2) {
      #pragma unroll
      for (int r = 0; r < 4; ++r) {
        float v = of[c2][r] + OF[(wq * 16 + quad * 4 + r) * 128 + c2 * 16 + n16];
        AO[(wq * 16 + quad * 4 + r) * 128 + c2 * 16 + n16] = f2bu(v * linv[r]);
      }
    }
  }
  __syncthreads();
  #pragma unroll
  for (int i = 0; i < 2; ++i) {
    int chunk = t + 512 * i;               // 1024 chunks of 8 shorts
    int q = chunk >> 4, dc = chunk & 15;
    u16x8 v = *(const u16x8*)&AO[q * 128 + dc * 8];
    *(u16x8*)&ao[((size_t)(nIdx * LQ + q0 + q)) * EMB + h * HD + dc * 8] = v;
  }
}

// ---------------- K3: output projection, 128x64 tiles, BK=64, dbuf glds -----
__global__ __launch_bounds__(256) void k_outproj(
    const unsigned short* __restrict__ ao, const unsigned short* __restrict__ Wob,
    const float* __restrict__ bo, float* __restrict__ out)
{
  __shared__ unsigned short As[2][128 * 64];   // slot=chunk^(row&7)
  __shared__ unsigned short Bs[2][64 * 64];
  int t = threadIdx.x;
  int w = t >> 6, lane = t & 63, quad = lane >> 4, n16 = lane & 15;
  int wm = w >> 1, wo = w & 1;
  int m0 = blockIdx.x * 128, o0 = blockIdx.y * 64;
  int ub = (t & 192);

  f32x4 of[4][2];
  #pragma unroll
  for (int a = 0; a < 4; ++a)
    { of[a][0] = (f32x4){0.f,0.f,0.f,0.f}; of[a][1] = (f32x4){0.f,0.f,0.f,0.f}; }

  #pragma unroll
  for (int i = 0; i < 4; ++i) {
    int ci = t + 256 * i;
    int row = ci >> 3, ch = (ci & 7) ^ (row & 7);
    glds16(&ao[(size_t)(m0 + row) * EMB + ch * 8], &As[0][(ub + 256 * i) * 8]);
  }
  #pragma unroll
  for (int i = 0; i < 2; ++i) {
    int ci = t + 256 * i;
    int row = ci >> 3, ch = (ci & 7) ^ (row & 7);
    glds16(&Wob[(size_t)(o0 + row) * EMB + ch * 8], &Bs[0][(ub + 256 * i) * 8]);
  }

  for (int kt = 0; kt < 32; ++kt) {
    int cur = kt & 1;
    __syncthreads();
    if (kt < 31) {
      int k1 = (kt + 1) * 64;
      #pragma unroll
      for (int i = 0; i < 4; ++i) {
        int ci = t + 256 * i;
        int row = ci >> 3, ch = (ci & 7) ^ (row & 7);
        glds16(&ao[(size_t)(m0 + row) * EMB + k1 + ch * 8], &As[1 - cur][(ub + 256 * i) * 8]);
      }
      #pragma unroll
      for (int i = 0; i < 2; ++i) {
        int ci = t + 256 * i;
        int row = ci >> 3, ch = (ci & 7) ^ (row & 7);
        glds16(&Wob[(size_t)(o0 + row) * EMB + k1 + ch * 8], &Bs[1 - cur][(ub + 256 * i) * 8]);
      }
    }
    #pragma unroll
    for (int kd = 0; kd < 2; ++kd) {
      int slot0 = (kd * 4 + quad);
      bf16x8 af[4], bf[2];
      #pragma unroll
      for (int a = 0; a < 4; ++a)
        af[a] = as_bf(*(const u16x8*)&As[cur][(wm * 64 + a * 16 + n16) * 64 + (slot0 ^ (n16 & 7)) * 8]);
      #pragma unroll
      for (int b = 0; b < 2; ++b)
        bf[b] = as_bf(*(const u16x8*)&Bs[cur][(wo * 32 + b * 16 + n16) * 64 + (slot0 ^ (n16 & 7)) * 8]);
      #pragma unroll
      for (int a = 0; a < 4; ++a)
        #pragma unroll
        for (int b = 0; b < 2; ++b)
          of[a][b] = __builtin_amdgcn_mfma_f32_16x16x32_bf16(af[a], bf[b], of[a][b], 0, 0, 0);
    }
  }

  float bb[2] = { bo[o0 + wo * 32 + n16], bo[o0 + wo * 32 + 16 + n16] };
  #pragma unroll
  for (int a = 0; a < 4; ++a) {
    #pragma unroll
    for (int b = 0; b < 2; ++b) {
      #pragma unroll
      for (int r = 0; r < 4; ++r) {
        out[(size_t)(m0 + wm * 64 + a * 16 + quad * 4 + r) * EMB
            + o0 + wo * 32 + b * 16 + n16] = of[a][b][r] + bb[b];
      }
    }
  }
}

extern "C" void kernel_launch(void* const* d_in, const int* in_sizes, int n_in,
                              void* d_out, int out_size, void* d_ws, size_t ws_size,
                              hipStream_t stream) {
  (void)in_sizes; (void)n_in; (void)out_size; (void)ws_size;
  const float* vals = (const float*)d_in[0];
  const float* keys = (const float*)d_in[1];
  const float* qrys = (const float*)d_in[2];
  const int*   mask = (const int*)d_in[3];
  const float* Wv   = (const float*)d_in[4];
  const float* Wk   = (const float*)d_in[5];
  const float* Wq   = (const float*)d_in[6];
  const float* Wo   = (const float*)d_in[7];
  const float* bo   = (const float*)d_in[8];
  float* out = (float*)d_out;

  unsigned short* U  = (unsigned short*)d_ws;
  unsigned short* qp = U;                              // (n,h,l,d) bf16
  unsigned short* kp = U + 4194304;
  unsigned short* vtF= U + 12582912;                   // fragment-ordered V tiles
  unsigned short* ao = U + 16777216;                   // (n,l,e) bf16
  unsigned short* Wob= U + 20971520;                   // Wo bf16
  unsigned long long* Mb = (unsigned long long*)(U + 25165824);  // 32768 u64

  k_proj    <<<dim3(512, 4), dim3(256), 0, stream>>>(vals, keys, qrys, Wv, Wk, Wq,
                                                     Wo, mask, kp, qp, vtF, Wob, Mb);
  k_attn    <<<dim3(16, 32), dim3(512), 0, stream>>>(qp, kp, vtF, Mb, ao);
  k_outproj <<<dim3(16, 32), dim3(256), 0, stream>>>(ao, Wob, bo, out);
}

// Round 11
// 187.561 us; speedup vs baseline: 1.0425x; 1.0425x over previous
//
#include <hip/hip_runtime.h>

#define LQ 1024
#define EMB 2048
#define NH 16
#define HD 128
#define RSCALE 0.022097086912079608f   /* 1/sqrt(2048) */

typedef unsigned short u16x8 __attribute__((ext_vector_type(8)));
typedef __bf16 bf16x8 __attribute__((ext_vector_type(8)));
typedef float f32x4 __attribute__((ext_vector_type(4)));
typedef short s16x4 __attribute__((ext_vector_type(4)));

typedef const __attribute__((address_space(1))) unsigned int* gas_t;
typedef __attribute__((address_space(3))) unsigned int* las_t;

__device__ __forceinline__ void glds16(const void* g, void* l){
  __builtin_amdgcn_global_load_lds((gas_t)g, (las_t)l, 16, 0, 0);
}
__device__ __forceinline__ unsigned short f2b(float f){
  unsigned int x = __float_as_uint(f);
  return (unsigned short)((x + 0x7fffu + ((x >> 16) & 1u)) >> 16);
}
// native RNE f32->bf16 (v_cvt on gfx950) — identical bits to f2b, 1 op not 4
__device__ __forceinline__ unsigned short f2bu(float f){
  union { __bf16 h; unsigned short u; } c; c.h = (__bf16)f; return c.u;
}
__device__ __forceinline__ short f2bs(float f){
  union { __bf16 h; short s; } c; c.h = (__bf16)f; return c.s;
}
__device__ __forceinline__ bf16x8 as_bf(u16x8 u){
  union { u16x8 u; bf16x8 b; } c; c.u = u; return c.b;
}
// K=16 bf16 MFMA (v_mfma_f32_16x16x16_bf16, gfx90a-lineage builtin, valid gfx950)
__device__ __forceinline__ f32x4 mfma16(s16x4 a, s16x4 b, f32x4 c){
  return __builtin_amdgcn_mfma_f32_16x16x16bf16_1k(a, b, c, 0, 0, 0);
}

// ---- K1 (fused): RoPE + projections + V-fragment emit + prep slice --------
// r11 (= r10 resubmit; round-10 bench was an infra container failure):
// 4 TILES PER BLOCK. grid (128, 4); each projection block stages W ONCE
// and projects 4 X-tiles (256 rows): W L2 traffic /4 (32->8 MB), and the
// whole grid (512 blocks) is a SINGLE co-resident generation (2 blocks/CU)
// — removes the 4-generation dispatch ramp (avg occupancy 18% << 50%).
//   y=0: V proj -> fragment-ordered vtF (block = one head, 4 k-tiles)
//   y=1: K proj (rope) -> kp   y=2: Q proj (rope,*RSCALE) -> qp
//   y=3: prep: Wo fp32->bf16 + mask bit-pack (8-deep batched ballots)
__global__ __launch_bounds__(256) void k_proj(
    const float* __restrict__ vals, const float* __restrict__ keys,
    const float* __restrict__ qrys,
    const float* __restrict__ Wv, const float* __restrict__ Wk,
    const float* __restrict__ Wq,
    const float* __restrict__ Wo, const int* __restrict__ M,
    unsigned short* __restrict__ kp, unsigned short* __restrict__ qp,
    unsigned short* __restrict__ vtF, unsigned short* __restrict__ Wob,
    unsigned long long* __restrict__ Mb)
{
  __shared__ unsigned short Xs[64 * 136];
  __shared__ unsigned short Ws[128 * 136];
  __shared__ float scC[16 * 128], scS[16 * 128];
  int t = threadIdx.x;
  int which = blockIdx.y;

  if (which == 3) {                       // ---- prep slice (4x work) ----
    int bx = blockIdx.x;
    #pragma unroll 4
    for (int k = 0; k < 32; ++k) {
      int i = (bx * 8192 + k * 256 + t) * 4;
      float4 f = *(const float4*)&Wo[i];
      ushort4 u;
      u.x = f2bu(f.x); u.y = f2bu(f.y); u.z = f2bu(f.z); u.w = f2bu(f.w);
      *(ushort4*)&Wob[i] = u;
    }
    int w = t >> 6, lane = t & 63;
    for (int i0 = 0; i0 < 64; i0 += 8) {  // 8 loads in flight per batch
      int v[8];
      #pragma unroll
      for (int j = 0; j < 8; ++j) {
        int w_idx = bx * 256 + w * 64 + i0 + j;
        int n = w_idx >> 14, row = (w_idx >> 4) & 1023, wc = w_idx & 15;
        v[j] = M[(size_t)n * (LQ * LQ) + (size_t)row * LQ + wc * 64 + lane];
      }
      #pragma unroll
      for (int j = 0; j < 8; ++j) {
        unsigned long long b = __ballot(v[j] != 0);
        if (lane == 0) Mb[bx * 256 + w * 64 + i0 + j] = b;
      }
    }
    return;
  }

  const float* X; const float* W; bool rope;
  if (which == 0)      { X = vals; W = Wv; rope = false; }
  else if (which == 1) { X = keys; W = Wk; rope = true;  }
  else                 { X = qrys; W = Wq; rope = true;  }
  float qs = (which == 2) ? RSCALE : 1.0f;

  int w = t >> 6, lane = t & 63, quad = lane >> 4, n16 = lane & 15;

  // stage W (fp32 -> bf16) into LDS — ONCE for all 4 tiles
  #pragma unroll
  for (int i = 0; i < 8; ++i) {
    int ci = t + 256 * i;
    int row = ci >> 4, ch = ci & 15;
    float4 a = *(const float4*)&W[row * 128 + ch * 8];
    float4 b = *(const float4*)&W[row * 128 + ch * 8 + 4];
    u16x8 u;
    u[0]=f2bu(a.x); u[1]=f2bu(a.y); u[2]=f2bu(a.z); u[3]=f2bu(a.w);
    u[4]=f2bu(b.x); u[5]=f2bu(b.y); u[6]=f2bu(b.z); u[7]=f2bu(b.w);
    *(u16x8*)&Ws[row * 136 + ch * 8] = u;
  }
  if (rope) {
    // sincos for all 16 l-values of this block (256 rows = 16 l x 16 h)
    int l0 = (blockIdx.x * 16) & 1023;
    #pragma unroll
    for (int i = 0; i < 8; ++i) {
      int idx = t + 256 * i;                 // < 2048 = 16 l x 128 d
      int li = idx >> 7, d = idx & 127, j = d & 63;
      float inv = 1.0f / powf(10000.0f, (float)(2 * j) * 0.0078125f);
      float ang = (float)(l0 + li) * inv;
      scC[idx] = cosf(ang);
      scS[idx] = sinf(ang);
    }
  }
  __syncthreads();

  int bh0 = blockIdx.x >> 2;              // V: head index (constant per block)
  for (int tile = 0; tile < 4; ++tile) {
    int bx4 = blockIdx.x * 4 + tile;
    int m0 = bx4 * 64;
    int kt0 = bx4 & 15;                   // V: k-tile index

    // stage X (fp32 -> bf16, rope applied for K/Q)
    if (which == 0) {
      int n = bh0 >> 4, h = bh0 & 15;
      #pragma unroll
      for (int i = 0; i < 8; ++i) {
        int fi = t + 256 * i;
        int row = fi >> 5, dq = (fi & 31) * 4;
        size_t gr = (size_t)n * 16384 + (size_t)(kt0 * 64 + row) * 16 + h;
        float4 x = *(const float4*)&X[gr * HD + dq];
        ushort4 u;
        u.x = f2bu(x.x); u.y = f2bu(x.y); u.z = f2bu(x.z); u.w = f2bu(x.w);
        *(ushort4*)&Xs[row * 136 + dq] = u;
      }
    } else {
      #pragma unroll
      for (int i = 0; i < 8; ++i) {
        int fi = t + 256 * i;
        int row = fi >> 5, dq = (fi & 31) * 4;
        int gr = m0 + row;
        float4 x = *(const float4*)&X[(size_t)gr * HD + dq];
        int li = tile * 4 + (row >> 4);
        float4 xm = *(const float4*)&X[(size_t)gr * HD + (124 - dq)];
        float4 c  = *(const float4*)&scC[li * 128 + dq];
        float4 s  = *(const float4*)&scS[li * 128 + dq];
        ushort4 u;
        u.x = f2bu(x.x * c.x + xm.w * s.x);
        u.y = f2bu(x.y * c.y + xm.z * s.y);
        u.z = f2bu(x.z * c.z + xm.y * s.z);
        u.w = f2bu(x.w * c.w + xm.x * s.w);
        *(ushort4*)&Xs[row * 136 + dq] = u;
      }
    }
    __syncthreads();

    f32x4 of[4][2];
    #pragma unroll
    for (int a = 0; a < 4; ++a)
      { of[a][0] = (f32x4){0.f,0.f,0.f,0.f}; of[a][1] = (f32x4){0.f,0.f,0.f,0.f}; }

    #pragma unroll
    for (int kd = 0; kd < 4; ++kd) {
      bf16x8 bfr[2];
      #pragma unroll
      for (int b2 = 0; b2 < 2; ++b2)
        bfr[b2] = as_bf(*(const u16x8*)&Ws[(w * 32 + b2 * 16 + n16) * 136 + kd * 32 + quad * 8]);
      #pragma unroll
      for (int a = 0; a < 4; ++a) {
        bf16x8 af = as_bf(*(const u16x8*)&Xs[(a * 16 + n16) * 136 + kd * 32 + quad * 8]);
        of[a][0] = __builtin_amdgcn_mfma_f32_16x16x32_bf16(af, bfr[0], of[a][0], 0, 0, 0);
        of[a][1] = __builtin_amdgcn_mfma_f32_16x16x32_bf16(af, bfr[1], of[a][1], 0, 0, 0);
      }
    }

    if (which == 0) {
      // V: fragment-ordered vtF, PAIRED layout (16B/lane coalesced).
      // of[a][b2][r] = V[kpos = a*16+quad*4+r][d = (w*2+b2)*16 + n16]
      size_t vbase = (size_t)bh0 * (LQ * HD) + (size_t)kt0 * 8192;
      #pragma unroll
      for (int a = 0; a < 4; ++a) {
        u16x8 u;
        u[0]=f2bu(of[a][0][0]); u[1]=f2bu(of[a][0][1]);
        u[2]=f2bu(of[a][0][2]); u[3]=f2bu(of[a][0][3]);
        u[4]=f2bu(of[a][1][0]); u[5]=f2bu(of[a][1][1]);
        u[6]=f2bu(of[a][1][2]); u[7]=f2bu(of[a][1][3]);
        *(u16x8*)&vtF[vbase + (size_t)(((a * 4 + w) * 64 + (quad * 16 + n16)) * 8)] = u;
      }
      __syncthreads();                     // Xs reads done before next stage
    } else {
      // K/Q: route fragments through Xs (dead after MFMA; Ws stays live)
      unsigned short* OUT = (which == 1) ? kp : qp;
      __syncthreads();                     // everyone done reading Xs
      #pragma unroll
      for (int a = 0; a < 4; ++a)
        #pragma unroll
        for (int b2 = 0; b2 < 2; ++b2)
          #pragma unroll
          for (int r = 0; r < 4; ++r)
            Xs[(a * 16 + quad * 4 + r) * 136 + w * 32 + b2 * 16 + n16] =
                f2bu(of[a][b2][r] * qs);
      __syncthreads();
      #pragma unroll
      for (int i = 0; i < 4; ++i) {
        int chunk = t + 256 * i;           // 1024 chunks of 8 shorts
        int row = chunk >> 4, dc = chunk & 15;
        u16x8 v = *(const u16x8*)&Xs[row * 136 + dc * 8];
        int m = m0 + row;
        int n = m >> 14, l = (m >> 4) & 1023, h = m & 15;
        *(u16x8*)&OUT[(((size_t)(n * NH + h)) * LQ + l) * HD + dc * 8] = v;
      }
      __syncthreads();                     // stores' Xs reads done before next stage
    }
  }
}

// ---------------- K2: MFMA flash attention, S^T trick, no P round-trip ------
// Fragment-ordered LDS tiles; PV ds_read_b128 paired; coalesced ao epilogue.
__global__ __launch_bounds__(512) void k_attn(
    const unsigned short* __restrict__ qp, const unsigned short* __restrict__ kp,
    const unsigned short* __restrict__ vtF, const unsigned long long* __restrict__ Mb,
    unsigned short* __restrict__ ao)
{
  __shared__ unsigned short KsF[2][8192];   // [tile][kd][c][lane] 16B chunks
  __shared__ unsigned short VsF[2][8192];   // [tile][c][c2p][lane] 16B paired slots
  __shared__ float ls[8][16];
  int t = threadIdx.x, w = t >> 6, lane = t & 63, quad = lane >> 4, n16 = lane & 15;
  int grp = w >> 2, wq = w & 3;                // k-group, q-row wave within group
  // XCD swizzle: cluster one head's q-tiles on one XCD so its K/V stays in L2.
  int lin = blockIdx.y * gridDim.x + blockIdx.x;
  int xcd = lin & 7, j = lin >> 3;
  int bh = xcd + 8 * (j >> 4);
  int q0 = (j & 15) * 64;
  int nIdx = bh >> 4, h = bh & 15;
  size_t base = (size_t)bh * LQ * HD;
  const unsigned short* Q = qp + base;
  const unsigned short* K = kp + base;
  const unsigned short* VF = vtF + base;       // fragment-ordered tiles

  // Q fragments (B-operand of S^T MFMA): B[n=q=n16][k=d=kd*32+quad*8+j]
  bf16x8 qf[4];
  #pragma unroll
  for (int kd = 0; kd < 4; ++kd)
    qf[kd] = as_bf(*(const u16x8*)&Q[(size_t)(q0 + wq * 16 + n16) * HD + kd * 32 + quad * 8]);

  // one mask word per lane per tile: q = n16
  const unsigned long long* MbRow =
      Mb + ((size_t)nIdx * LQ + q0 + wq * 16 + n16) * 16;

  f32x4 of[8];
  #pragma unroll
  for (int c = 0; c < 8; ++c) of[c] = (f32x4){0.f, 0.f, 0.f, 0.f};
  float lp = 0.f;                          // per-lane partial of l[q=n16]

  for (int p = 0; p < 8; ++p) {
    int k0 = p * 128;
    __syncthreads();                       // all waves done reading both buffers
    // stage tile pair (2p -> buf0, 2p+1 -> buf1), all 8 waves cooperate
    #pragma unroll
    for (int jj = 0; jj < 2; ++jj) {
      int kt = 2 * p + jj;
      #pragma unroll
      for (int i = 0; i < 2; ++i) {
        int D = t + 512 * i;               // 16B chunk id 0..1023
        int nn = D & 15, qq = (D >> 4) & 3, cc = (D >> 6) & 3, kd = D >> 8;
        glds16(&K[(size_t)(k0 + jj * 64 + cc * 16 + nn) * HD + (kd * 4 + qq) * 8],
               &KsF[jj][(size_t)D * 8]);
        glds16(&VF[(size_t)kt * 8192 + (size_t)D * 8],
               &VsF[jj][(size_t)D * 8]);
      }
    }
    unsigned long long mq = MbRow[2 * p + grp];
    __syncthreads();                       // implicit vmcnt(0): staged data ready

    // single variable 64-bit shift; per-bit extracts below are const-shift
    unsigned long long msh = mq >> (quad * 4);

    // ---- S^T = K Q^T : rows kpos, cols q (group's own tile) ----
    f32x4 sf[4];
    #pragma unroll
    for (int c = 0; c < 4; ++c) sf[c] = (f32x4){0.f, 0.f, 0.f, 0.f};
    __builtin_amdgcn_s_setprio(1);
    #pragma unroll
    for (int kd = 0; kd < 4; ++kd) {
      #pragma unroll
      for (int c = 0; c < 4; ++c) {
        bf16x8 kv = as_bf(*(const u16x8*)&KsF[grp][((kd * 4 + c) * 64 + lane) * 8]);
        sf[c] = __builtin_amdgcn_mfma_f32_16x16x32_bf16(kv, qf[kd], sf[c], 0, 0, 0);
      }
    }
    __builtin_amdgcn_s_setprio(0);
    // ---- softmax numerators + PV (P stays in registers) ----
    #pragma unroll
    for (int c = 0; c < 4; ++c) {
      s16x4 pa;
      #pragma unroll
      for (int r = 0; r < 4; ++r) {
        int bit = (int)((msh >> (c * 16 + r)) & 1ull);
        float p = bit ? __expf(sf[c][r]) : 0.f;
        lp += p;
        pa[r] = f2bs(p);
      }
      __builtin_amdgcn_s_setprio(1);
      #pragma unroll
      for (int c2p = 0; c2p < 4; ++c2p) {
        u16x8 vv2 = *(const u16x8*)&VsF[grp][((c * 4 + c2p) * 64 + lane) * 8];
        s16x4 vlo = { (short)vv2[0], (short)vv2[1], (short)vv2[2], (short)vv2[3] };
        s16x4 vhi = { (short)vv2[4], (short)vv2[5], (short)vv2[6], (short)vv2[7] };
        of[2 * c2p]     = mfma16(pa, vlo, of[2 * c2p]);
        of[2 * c2p + 1] = mfma16(pa, vhi, of[2 * c2p + 1]);
      }
      __builtin_amdgcn_s_setprio(0);
    }
  }

  // ---- combine: l via ls; of via 32KB OF overlay (KsF); normalized bf16
  // result via 16KB AO overlay (VsF) -> coalesced 16B stores by all waves.
  __syncthreads();                         // all compute done before overlays
  {
    float s = lp;
    s += __shfl_xor(s, 16);
    s += __shfl_xor(s, 32);
    ls[w][n16] = s;
  }
  float* OF = (float*)&KsF[0][0];          // 64 q x 128 d f32 = 32 KB
  unsigned short* AO = &VsF[0][0];         // 64 q x 128 d bf16 = 16 KB
  if (grp == 1) {
    #pragma unroll
    for (int c2 = 0; c2 < 8; ++c2) {
      #pragma unroll
      for (int r = 0; r < 4; ++r) {
        OF[(wq * 16 + quad * 4 + r) * 128 + c2 * 16 + n16] = of[c2][r];
      }
    }
  }
  __syncthreads();
  if (grp == 0) {
    float linv[4];
    #pragma unroll
    for (int r = 0; r < 4; ++r)
      linv[r] = 1.0f / fmaxf(ls[wq][quad * 4 + r] + ls[wq + 4][quad * 4 + r], 1e-30f);
    #pragma unroll
    for (int c2 = 0; c2 < 8; ++c2) {
      #pragma unroll
      for (int r = 0; r < 4; ++r) {
        float v = of[c2][r] + OF[(wq * 16 + quad * 4 + r) * 128 + c2 * 16 + n16];
        AO[(wq * 16 + quad * 4 + r) * 128 + c2 * 16 + n16] = f2bu(v * linv[r]);
      }
    }
  }
  __syncthreads();
  #pragma unroll
  for (int i = 0; i < 2; ++i) {
    int chunk = t + 512 * i;               // 1024 chunks of 8 shorts
    int q = chunk >> 4, dc = chunk & 15;
    u16x8 v = *(const u16x8*)&AO[q * 128 + dc * 8];
    *(u16x8*)&ao[((size_t)(nIdx * LQ + q0 + q)) * EMB + h * HD + dc * 8] = v;
  }
}

// ---------------- K3: output projection, 128x64 tiles, BK=64, dbuf glds -----
__global__ __launch_bounds__(256) void k_outproj(
    const unsigned short* __restrict__ ao, const unsigned short* __restrict__ Wob,
    const float* __restrict__ bo, float* __restrict__ out)
{
  __shared__ unsigned short As[2][128 * 64];   // slot=chunk^(row&7)
  __shared__ unsigned short Bs[2][64 * 64];
  int t = threadIdx.x;
  int w = t >> 6, lane = t & 63, quad = lane >> 4, n16 = lane & 15;
  int wm = w >> 1, wo = w & 1;
  int m0 = blockIdx.x * 128, o0 = blockIdx.y * 64;
  int ub = (t & 192);

  f32x4 of[4][2];
  #pragma unroll
  for (int a = 0; a < 4; ++a)
    { of[a][0] = (f32x4){0.f,0.f,0.f,0.f}; of[a][1] = (f32x4){0.f,0.f,0.f,0.f}; }

  #pragma unroll
  for (int i = 0; i < 4; ++i) {
    int ci = t + 256 * i;
    int row = ci >> 3, ch = (ci & 7) ^ (row & 7);
    glds16(&ao[(size_t)(m0 + row) * EMB + ch * 8], &As[0][(ub + 256 * i) * 8]);
  }
  #pragma unroll
  for (int i = 0; i < 2; ++i) {
    int ci = t + 256 * i;
    int row = ci >> 3, ch = (ci & 7) ^ (row & 7);
    glds16(&Wob[(size_t)(o0 + row) * EMB + ch * 8], &Bs[0][(ub + 256 * i) * 8]);
  }

  for (int kt = 0; kt < 32; ++kt) {
    int cur = kt & 1;
    __syncthreads();
    if (kt < 31) {
      int k1 = (kt + 1) * 64;
      #pragma unroll
      for (int i = 0; i < 4; ++i) {
        int ci = t + 256 * i;
        int row = ci >> 3, ch = (ci & 7) ^ (row & 7);
        glds16(&ao[(size_t)(m0 + row) * EMB + k1 + ch * 8], &As[1 - cur][(ub + 256 * i) * 8]);
      }
      #pragma unroll
      for (int i = 0; i < 2; ++i) {
        int ci = t + 256 * i;
        int row = ci >> 3, ch = (ci & 7) ^ (row & 7);
        glds16(&Wob[(size_t)(o0 + row) * EMB + k1 + ch * 8], &Bs[1 - cur][(ub + 256 * i) * 8]);
      }
    }
    #pragma unroll
    for (int kd = 0; kd < 2; ++kd) {
      int slot0 = (kd * 4 + quad);
      bf16x8 af[4], bf[2];
      #pragma unroll
      for (int a = 0; a < 4; ++a)
        af[a] = as_bf(*(const u16x8*)&As[cur][(wm * 64 + a * 16 + n16) * 64 + (slot0 ^ (n16 & 7)) * 8]);
      #pragma unroll
      for (int b = 0; b < 2; ++b)
        bf[b] = as_bf(*(const u16x8*)&Bs[cur][(wo * 32 + b * 16 + n16) * 64 + (slot0 ^ (n16 & 7)) * 8]);
      #pragma unroll
      for (int a = 0; a < 4; ++a)
        #pragma unroll
        for (int b = 0; b < 2; ++b)
          of[a][b] = __builtin_amdgcn_mfma_f32_16x16x32_bf16(af[a], bf[b], of[a][b], 0, 0, 0);
    }
  }

  float bb[2] = { bo[o0 + wo * 32 + n16], bo[o0 + wo * 32 + 16 + n16] };
  #pragma unroll
  for (int a = 0; a < 4; ++a) {
    #pragma unroll
    for (int b = 0; b < 2; ++b) {
      #pragma unroll
      for (int r = 0; r < 4; ++r) {
        out[(size_t)(m0 + wm * 64 + a * 16 + quad * 4 + r) * EMB
            + o0 + wo * 32 + b * 16 + n16] = of[a][b][r] + bb[b];
      }
    }
  }
}

extern "C" void kernel_launch(void* const* d_in, const int* in_sizes, int n_in,
                              void* d_out, int out_size, void* d_ws, size_t ws_size,
                              hipStream_t stream) {
  (void)in_sizes; (void)n_in; (void)out_size; (void)ws_size;
  const float* vals = (const float*)d_in[0];
  const float* keys = (const float*)d_in[1];
  const float* qrys = (const float*)d_in[2];
  const int*   mask = (const int*)d_in[3];
  const float* Wv   = (const float*)d_in[4];
  const float* Wk   = (const float*)d_in[5];
  const float* Wq   = (const float*)d_in[6];
  const float* Wo   = (const float*)d_in[7];
  const float* bo   = (const float*)d_in[8];
  float* out = (float*)d_out;

  unsigned short* U  = (unsigned short*)d_ws;
  unsigned short* qp = U;                              // (n,h,l,d) bf16
  unsigned short* kp = U + 4194304;
  unsigned short* vtF= U + 12582912;                   // fragment-ordered V tiles
  unsigned short* ao = U + 16777216;                   // (n,l,e) bf16
  unsigned short* Wob= U + 20971520;                   // Wo bf16
  unsigned long long* Mb = (unsigned long long*)(U + 25165824);  // 32768 u64

  k_proj    <<<dim3(128, 4), dim3(256), 0, stream>>>(vals, keys, qrys, Wv, Wk, Wq,
                                                     Wo, mask, kp, qp, vtF, Wob, Mb);
  k_attn    <<<dim3(16, 32), dim3(512), 0, stream>>>(qp, kp, vtF, Mb, ao);
  k_outproj <<<dim3(16, 32), dim3(256), 0, stream>>>(ao, Wob, bo, out);
}